// Round 6
// baseline (328.070 us; speedup 1.0000x reference)
//
#include <hip/hip_runtime.h>
#include <math.h>

#define N_NODES 20000
#define IN_DIM  256
#define OUT_DIM 128
#define S_SECT  8
#define K_BR    9
#define NK      (K_BR*OUT_DIM)   // 1152
#define EP_EDGE 40000
#define N_EDGES (S_SECT*EP_EDGE) // 320000
#define N_BINS  (S_SECT*N_NODES) // 160000
#define SCAN_BLOCKS 160
#define M_ROWS  (N_NODES*K_BR)   // 180000
#define ZP      136              // B LDS pitch (shorts): 272B, 16B-aligned, 2-way banks (free)
#define TP      136              // Z-tile pitch (shorts), bank-safe for gram-phase frag reads

typedef float v4f __attribute__((ext_vector_type(4)));
typedef short v8s __attribute__((ext_vector_type(8)));

__device__ inline unsigned short f2bf(float f) {
  union { float f; unsigned u; } v; v.f = f;
  unsigned r = v.u + 0x7fff + ((v.u >> 16) & 1);   // RNE
  return (unsigned short)(r >> 16);
}
__device__ inline float bf2f(unsigned short h) {
  union { unsigned u; float f; } v; v.u = ((unsigned)h) << 16;
  return v.f;
}

// merged prep: Wtg[j][k] = bf16(Wcat[k][j]) then Btg[n][k] = bf16([WC|WD][k][n])
__global__ __launch_bounds__(256) void k_prep(
    const float* __restrict__ Wself, const float* __restrict__ Wsect,
    const float* __restrict__ WC, const float* __restrict__ WD,
    unsigned short* __restrict__ Wtg, unsigned short* __restrict__ Btg)
{
  const int id = blockIdx.x * 256 + threadIdx.x;      // 294912 + 32768
  if (id < NK*IN_DIM) {
    const int j = id >> 8, k = id & 255;
    float w;
    if (j < OUT_DIM) w = Wself[(size_t)k*OUT_DIM + j];
    else {
      const int s = (j - OUT_DIM) >> 7, c = (j - OUT_DIM) & 127;
      w = Wsect[(size_t)s*(IN_DIM*OUT_DIM) + (size_t)k*OUT_DIM + c];
    }
    Wtg[id] = f2bf(w);
  } else {
    const int id2 = id - NK*IN_DIM;
    if (id2 < 256*128) {
      const int n = id2 >> 7, k = id2 & 127;
      const float w = (n < OUT_DIM) ? WC[k*OUT_DIM + n] : WD[k*OUT_DIM + (n - OUT_DIM)];
      Btg[id2] = f2bf(w);
    }
  }
}

// ---------------------------------------------------------------------------
// Kernel A (MFMA+LDS): P = x @ Wtg^T.
// Grid (313,3): 64 rows/block (4 waves x 16 rows), 3 branches per block.
// ---------------------------------------------------------------------------
__global__ __launch_bounds__(256, 4) void k_gemm_xw_mfma(
    const float* __restrict__ x, const unsigned short* __restrict__ Wtg,
    const float* __restrict__ outn, const float* __restrict__ inn,
    unsigned short* __restrict__ Hbuf, unsigned short* __restrict__ Zbufh)
{
  __shared__ unsigned short Bls[128*ZP];   // 34816 B
  const int t = threadIdx.x;
  const int wave = t >> 6, lane = t & 63;
  const int mrow = lane & 15, quad = lane >> 4;
  const int m0 = blockIdx.x * 64 + wave * 16;

  // A fragments, full K (32 VGPR), converted once
  v8s afr[8];
  {
    const int r = m0 + mrow;
    const bool ok = (r < N_NODES);
    const float* src = x + (size_t)r*IN_DIM + quad*8;
    #pragma unroll
    for (int kq = 0; kq < 8; ++kq) {
      float4 a0 = {0.f,0.f,0.f,0.f}, a1 = {0.f,0.f,0.f,0.f};
      if (ok) {
        a0 = *(const float4*)(src + kq*32);
        a1 = *(const float4*)(src + kq*32 + 4);
      }
      v8s f;
      f[0] = (short)f2bf(a0.x); f[1] = (short)f2bf(a0.y);
      f[2] = (short)f2bf(a0.z); f[3] = (short)f2bf(a0.w);
      f[4] = (short)f2bf(a1.x); f[5] = (short)f2bf(a1.y);
      f[6] = (short)f2bf(a1.z); f[7] = (short)f2bf(a1.w);
      afr[kq] = f;
    }
  }

  for (int jj = 0; jj < 3; ++jj) {
    const int jb = blockIdx.y * 3 + jj;       // global branch 0..8

    v4f acc[8];
    #pragma unroll
    for (int jt = 0; jt < 8; ++jt) acc[jt] = (v4f){0.f,0.f,0.f,0.f};

    for (int kh = 0; kh < 2; ++kh) {
      #pragma unroll
      for (int i = 0; i < 8; ++i) {
        const int idx = t + i*256;            // 0..2047
        const int row = idx >> 4, c8 = idx & 15;
        *(uint4*)(Bls + row*ZP + c8*8) =
            *(const uint4*)(Wtg + (size_t)(jb*128 + row)*IN_DIM + kh*128 + c8*8);
      }
      __syncthreads();

      #pragma unroll
      for (int kq = 0; kq < 4; ++kq) {
        #pragma unroll
        for (int jt = 0; jt < 8; ++jt) {
          const v8s bf = *(const v8s*)(Bls + (jt*16 + mrow)*ZP + kq*32 + quad*8);
          acc[jt] = __builtin_amdgcn_mfma_f32_16x16x32_bf16(afr[kh*4 + kq], bf, acc[jt], 0, 0, 0);
        }
      }
      __syncthreads();   // protect LDS before restaging
    }

    if (jb == 0) {
      #pragma unroll
      for (int p = 0; p < 4; ++p) {
        const int R = m0 + quad*4 + p;
        if (R >= N_NODES) continue;
        const float iw = inn[R];
        #pragma unroll
        for (int jt = 0; jt < 8; ++jt)
          Zbufh[(size_t)R*NK + jt*16 + mrow] = f2bf(acc[jt][p] * iw);
      }
    } else {
      const int s = jb - 1;
      #pragma unroll
      for (int p = 0; p < 4; ++p) {
        const int R = m0 + quad*4 + p;
        if (R >= N_NODES) continue;
        const float ow = outn[R];
        #pragma unroll
        for (int jt = 0; jt < 8; ++jt)
          Hbuf[((size_t)s*N_NODES + R)*OUT_DIM + jt*16 + mrow] = f2bf(acc[jt][p] * ow);
      }
    }
  }
}

// ---------------------------------------------------------------------------
// CSR build: count -> scan(3) -> scatter
// ---------------------------------------------------------------------------
__global__ __launch_bounds__(256) void k_count(
    const int* __restrict__ rows, int* __restrict__ cnt)
{
  const int id = blockIdx.x * 256 + threadIdx.x;
  if (id >= N_EDGES) return;
  const int s = id / EP_EDGE;
  atomicAdd(&cnt[s * N_NODES + rows[id]], 1);
}

__global__ __launch_bounds__(256) void k_scan1(
    const int* __restrict__ cnt, int* __restrict__ bsum)
{
  __shared__ int sh[256];
  const int t = threadIdx.x;
  const int base = blockIdx.x * 1000;
  int s = 0;
  if (t < 250) {
    const int i = base + t*4;
    s = cnt[i] + cnt[i+1] + cnt[i+2] + cnt[i+3];
  }
  sh[t] = s; __syncthreads();
  for (int off = 128; off > 0; off >>= 1) {
    if (t < off) sh[t] += sh[t + off];
    __syncthreads();
  }
  if (t == 0) bsum[blockIdx.x] = sh[0];
}

__global__ void k_scan2(const int* __restrict__ bsum, int* __restrict__ boff)
{
  if (threadIdx.x == 0) {
    int acc = 0;
    for (int b = 0; b < SCAN_BLOCKS; ++b) { boff[b] = acc; acc += bsum[b]; }
  }
}

__global__ __launch_bounds__(256) void k_scan3(
    const int* __restrict__ cnt, const int* __restrict__ boff,
    int* __restrict__ offs)
{
  __shared__ int sh[256];
  const int t = threadIdx.x;
  const int base = blockIdx.x * 1000;
  int v[4] = {0,0,0,0};
  int mySum = 0;
  if (t < 250) {
    const int i = base + t*4;
    v[0]=cnt[i]; v[1]=cnt[i+1]; v[2]=cnt[i+2]; v[3]=cnt[i+3];
    mySum = v[0]+v[1]+v[2]+v[3];
  }
  sh[t] = mySum; __syncthreads();
  for (int off = 1; off < 256; off <<= 1) {
    int add = (t >= off) ? sh[t - off] : 0;
    __syncthreads();
    sh[t] += add;
    __syncthreads();
  }
  if (t < 250) {
    int excl = boff[blockIdx.x] + sh[t] - mySum;
    const int i = base + t*4;
    offs[i]   = excl;           excl += v[0];
    offs[i+1] = excl;           excl += v[1];
    offs[i+2] = excl;           excl += v[2];
    offs[i+3] = excl;
  }
}

__global__ __launch_bounds__(256) void k_scatter(
    const int* __restrict__ rows, const int* __restrict__ cols,
    const int* __restrict__ offs, int* __restrict__ cur,
    int* __restrict__ eCol)
{
  const int id = blockIdx.x * 256 + threadIdx.x;
  if (id >= N_EDGES) return;
  const int s = id / EP_EDGE;
  const int bin = s * N_NODES + rows[id];
  const int pos = offs[bin] + atomicAdd(&cur[bin], 1);
  eCol[pos] = cols[id];
}

// ---------------------------------------------------------------------------
// Kernel B': pull aggregation from bf16 Hbuf; fold in_norm; bf16 store.
// ---------------------------------------------------------------------------
__global__ __launch_bounds__(256) void k_agg_csr(
    const unsigned short* __restrict__ Hbuf, const int* __restrict__ offs,
    const int* __restrict__ cnt, const int* __restrict__ eCol,
    const float* __restrict__ inn, unsigned short* __restrict__ Zbufh)
{
  const long long tid = (long long)blockIdx.x * 256 + threadIdx.x;
  const int group = (int)(tid >> 5);
  if (group >= N_BINS) return;
  const int lane = (int)(tid & 31);
  const int s = group / N_NODES;
  const int r = group - s * N_NODES;
  const int start = offs[group];
  const int n = cnt[group];
  float4 acc = {0.f, 0.f, 0.f, 0.f};
  for (int i = 0; i < n; ++i) {
    const int c = eCol[start + i];
    const uint2 h = *(const uint2*)(Hbuf + ((size_t)s*N_NODES + c)*OUT_DIM + lane*4);
    acc.x += bf2f((unsigned short)h.x);
    acc.y += bf2f((unsigned short)(h.x >> 16));
    acc.z += bf2f((unsigned short)h.y);
    acc.w += bf2f((unsigned short)(h.y >> 16));
  }
  const float w = inn[r];
  uint2 o;
  o.x = (unsigned)f2bf(acc.x * w) | ((unsigned)f2bf(acc.y * w) << 16);
  o.y = (unsigned)f2bf(acc.z * w) | ((unsigned)f2bf(acc.w * w) << 16);
  *(uint2*)(Zbufh + ((size_t)r*K_BR + 1 + s)*OUT_DIM + lane*4) = o;
}

// ---------------------------------------------------------------------------
// k_zcd_interact: FUSED [zc|zd] GEMM + gram + softmax + combine + gate.
// 8 nodes / 256 threads / 4 waves; wave w owns nodes 2w,2w+1 everywhere.
// BARRIER-FREE: B-frags read from global Btg (64 KB, L1/L2 broadcast across
// all waves), all LDS (tls/graw/gs) is wave-partitioned; same-wave DS ops
// are ordered by the in-order LDS pipe.
// GEMM uses SWAPPED mfma operands -> transposed acc: each lane holds 4
// consecutive channels of one z-row -> packed ds_write_b64 tls stores
// (replaces 64 scalar b16 stores/lane that caused 3.08M bank conflicts).
// f2bf rounding points identical to the unfused ZCD path.
// LDS 49.5 KB -> 3 blocks/CU (12 waves/CU).
// ---------------------------------------------------------------------------
__global__ __launch_bounds__(256, 3) void k_zcd_interact(
    const unsigned short* __restrict__ Zbufh, const unsigned short* __restrict__ Btg,
    const float* __restrict__ gw, const float* __restrict__ gb,
    float* __restrict__ out)
{
  __shared__ unsigned short tls[8][2][9*TP];   // 39168 B (wave-private slices)
  __shared__ float graw[8][2][K_BR][10];       // 5760 B
  __shared__ float gs[8][2][K_BR][10];         // 5760 B
  const int t = threadIdx.x;
  const int wv = t >> 6, lane = t & 63;
  const int mrow = lane & 15, quad = lane >> 4;
  const int n0 = blockIdx.x * 8;
  const int rowbase = (n0 + 2*wv)*9;

  // ---- A-frags: the wave's 18 rows of Zbufh (2 M-tiles: 16 + 2)
  v8s afr[2][4];
  #pragma unroll
  for (int rb = 0; rb < 2; ++rb) {
    const int rloc = rb*16 + mrow;
    const bool ok = (rloc < 18);
    const unsigned short* src = Zbufh + (size_t)(rowbase + rloc)*OUT_DIM + quad*8;
    #pragma unroll
    for (int kq = 0; kq < 4; ++kq) {
      v8s f = {0,0,0,0,0,0,0,0};
      if (ok) f = *(const v8s*)(src + kq*32);
      afr[rb][kq] = f;
    }
  }

  // ---- GEMM phase: zc (jh=0) then zd (jh=1), swapped operands, acc -> tls
  for (int jh = 0; jh < 2; ++jh) {
    v4f acc[2][8];
    #pragma unroll
    for (int rb = 0; rb < 2; ++rb)
      #pragma unroll
      for (int j = 0; j < 8; ++j) acc[rb][j] = (v4f){0.f,0.f,0.f,0.f};

    #pragma unroll
    for (int j = 0; j < 8; ++j) {
      // B-frag: Btg row n = jh*128 + j*16 + mrow, k = kq*32 + quad*8.
      const unsigned short* bp = Btg + (size_t)(jh*128 + j*16 + mrow)*OUT_DIM + quad*8;
      #pragma unroll
      for (int kq = 0; kq < 4; ++kq) {
        const v8s bf = *(const v8s*)(bp + kq*32);
        // swapped: D[n][m] -> lane holds n = j*16+quad*4+p, m = rb*16+mrow
        acc[0][j] = __builtin_amdgcn_mfma_f32_16x16x32_bf16(bf, afr[0][kq], acc[0][j], 0, 0, 0);
        acc[1][j] = __builtin_amdgcn_mfma_f32_16x16x32_bf16(bf, afr[1][kq], acc[1][j], 0, 0, 0);
      }
    }

    // store: packed b64 per (rb,j); same f2bf rounding as old ZCD store.
    #pragma unroll
    for (int rb = 0; rb < 2; ++rb) {
      const int m = rb*16 + mrow;          // z-row within the wave's 18
      if (m < 18) {
        const int nn = (m >= 9) ? 1 : 0;
        const int kk = m - nn*9;
        unsigned short* dst = &tls[wv*2 + nn][jh][kk*TP];
        #pragma unroll
        for (int j = 0; j < 8; ++j) {
          uint2 o;
          o.x = (unsigned)f2bf(acc[rb][j][0]) | ((unsigned)f2bf(acc[rb][j][1]) << 16);
          o.y = (unsigned)f2bf(acc[rb][j][2]) | ((unsigned)f2bf(acc[rb][j][3]) << 16);
          *(uint2*)(dst + j*16 + quad*4) = o;
        }
      }
    }
  }
  // tls is wave-private; same-wave DS ordering makes it visible. No barriers.

  // ---- gram phase: G = Z·Z^T via MFMA, frags re-read from tls
  {
    const int r = lane & 15;
    #pragma unroll
    for (int q = 0; q < 4; ++q) {
      const int node = wv*2 + (q >> 1), mat = q & 1;
      const unsigned short* src = &tls[node][mat][r*TP + quad*8];
      v8s frag[4];
      #pragma unroll
      for (int kq = 0; kq < 4; ++kq) {
        v8s f = {0,0,0,0,0,0,0,0};
        if (r < K_BR) f = *(const v8s*)(src + kq*32);
        frag[kq] = f;
      }
      v4f acc = {0.f,0.f,0.f,0.f};
      #pragma unroll
      for (int kq = 0; kq < 4; ++kq)
        acc = __builtin_amdgcn_mfma_f32_16x16x32_bf16(frag[kq], frag[kq], acc, 0, 0, 0);
      if (r < K_BR) {
        #pragma unroll
        for (int p = 0; p < 4; ++p) {
          const int m = quad*4 + p;
          if (m < K_BR) graw[node][mat][m][r] = acc[p];
        }
      }
    }
  }

  // ---- softmax phase: wave-local (lanes 0..35 cover 2 nodes x 2 mats x 9)
  if (lane < 36) {
    const int nn2  = (lane >= 18) ? 1 : 0;
    const int node = wv*2 + nn2;
    const int rem  = lane - nn2*18;
    const int mat  = (rem >= 9) ? 1 : 0;
    const int k    = rem - mat*9;
    float v[9];
    if (mat == 0) {
      #pragma unroll
      for (int j = 0; j < 9; ++j) v[j] = graw[node][0][k][j];
    } else {
      const float gkk = graw[node][1][k][k];
      #pragma unroll
      for (int j = 0; j < 9; ++j) v[j] = gkk - graw[node][1][k][j];
    }
    float m = v[0];
    #pragma unroll
    for (int j = 1; j < 9; ++j) m = fmaxf(m, v[j]);
    float sum = 0.f;
    #pragma unroll
    for (int j = 0; j < 9; ++j) { v[j] = expf(v[j] - m); sum += v[j]; }
    const float inv = 1.f / sum;
    #pragma unroll
    for (int j = 0; j < 9; ++j) gs[node][mat][k][j] = v[j] * inv;
  }

  // ---- combine + gate, wave-local, barrier-free
  const float gbv = gb[0];
  float gwc[2][9], gwd[2][9];
  #pragma unroll
  for (int dd = 0; dd < 2; ++dd) {
    const int d = lane + dd*64;
    #pragma unroll
    for (int j = 0; j < 9; ++j) {
      gwc[dd][j] = gw[j*OUT_DIM + d];
      gwd[dd][j] = gw[NK + j*OUT_DIM + d];
    }
  }

  for (int nn = 0; nn < 2; ++nn) {
    const int node = wv*2 + nn;
    float zcj[2][9], zdj[2][9];
    #pragma unroll
    for (int dd = 0; dd < 2; ++dd) {
      const int d = lane + dd*64;
      #pragma unroll
      for (int j = 0; j < 9; ++j) {
        zcj[dd][j] = bf2f(tls[node][0][j*TP + d]);
        zdj[dd][j] = bf2f(tls[node][1][j*TP + d]);
      }
    }
    float zcomK[2][9], zdisK[2][9];
    float gp = 0.f;
    #pragma unroll
    for (int k = 0; k < 9; ++k) {
      #pragma unroll
      for (int dd = 0; dd < 2; ++dd) {
        float zc = 0.f, ad = 0.f;
        #pragma unroll
        for (int j = 0; j < 9; ++j) {
          zc += gs[node][0][k][j] * zcj[dd][j];
          ad += gs[node][1][k][j] * zdj[dd][j];
        }
        zcomK[dd][k] = zc;
        zdisK[dd][k] = zdj[dd][k] - ad;
        gp += zc * gwc[dd][k] + zdisK[dd][k] * gwd[dd][k];
      }
    }
    #pragma unroll
    for (int off = 32; off > 0; off >>= 1) gp += __shfl_xor(gp, off, 64);
    const float beta = 1.f / (1.f + expf(-(gp + gbv)));
    #pragma unroll
    for (int k = 0; k < 9; ++k) {
      #pragma unroll
      for (int dd = 0; dd < 2; ++dd) {
        const int d = lane + dd*64;
        out[(size_t)(n0+node)*NK + k*OUT_DIM + d] =
            beta*zcomK[dd][k] + (1.f-beta)*zdisK[dd][k];
      }
    }
  }
}

// ---------------------------------------------------------------------------
extern "C" void kernel_launch(void* const* d_in, const int* in_sizes, int n_in,
                              void* d_out, int out_size, void* d_ws, size_t ws_size,
                              hipStream_t stream)
{
  const float* x     = (const float*)d_in[0];
  const float* Wself = (const float*)d_in[1];
  const float* Wsect = (const float*)d_in[2];
  const float* WC    = (const float*)d_in[3];
  const float* WD    = (const float*)d_in[4];
  const float* gw    = (const float*)d_in[5];
  const float* gb    = (const float*)d_in[6];
  const float* outn  = (const float*)d_in[7];
  const float* inn   = (const float*)d_in[8];
  const int*   rows  = (const int*)d_in[9];
  const int*   cols  = (const int*)d_in[10];
  float* out = (float*)d_out;

  char* p = (char*)d_ws;
  unsigned short* Hbuf  = (unsigned short*)p; p += (size_t)S_SECT*N_NODES*OUT_DIM*2;
  unsigned short* Zbufh = (unsigned short*)p; p += (size_t)M_ROWS*OUT_DIM*2;
  int* cnt    = (int*)p;                      p += (size_t)N_BINS*4;
  int* offs   = (int*)p;                      p += (size_t)N_BINS*4;
  int* cur    = (int*)p;                      p += (size_t)N_BINS*4;
  int* bsum   = (int*)p;                      p += 256*4;
  int* boff   = (int*)p;                      p += 256*4;
  int* eCol   = (int*)p;                      p += (size_t)N_EDGES*4;
  unsigned short* Btg = (unsigned short*)p;   p += 256*128*2;
  unsigned short* Wtg = (unsigned short*)p;   p += (size_t)NK*IN_DIM*2;

  hipMemsetAsync(cnt, 0, (size_t)N_BINS*4, stream);
  hipMemsetAsync(cur, 0, (size_t)N_BINS*4, stream);

  k_prep<<<(NK*IN_DIM + 256*128 + 255)/256, 256, 0, stream>>>(Wself, Wsect, WC, WD, Wtg, Btg);

  dim3 gA((N_NODES + 63)/64, 3);   // 313 x 3
  k_gemm_xw_mfma<<<gA, 256, 0, stream>>>(x, Wtg, outn, inn, Hbuf, Zbufh);

  const int eb = (N_EDGES + 255)/256;
  k_count  <<<eb, 256, 0, stream>>>(rows, cnt);
  k_scan1  <<<SCAN_BLOCKS, 256, 0, stream>>>(cnt, bsum);
  k_scan2  <<<1, 64, 0, stream>>>(bsum, boff);
  k_scan3  <<<SCAN_BLOCKS, 256, 0, stream>>>(cnt, boff, offs);
  k_scatter<<<eb, 256, 0, stream>>>(rows, cols, offs, cur, eCol);

  const int aggBlocks = (N_BINS*32 + 255)/256;
  k_agg_csr<<<aggBlocks, 256, 0, stream>>>(Hbuf, offs, cnt, eCol, inn, Zbufh);

  k_zcd_interact<<<N_NODES/8, 256, 0, stream>>>(Zbufh, Btg, gw, gb, out);
}

// Round 7
// 291.971 us; speedup vs baseline: 1.1236x; 1.1236x over previous
//
#include <hip/hip_runtime.h>
#include <math.h>

#define N_NODES 20000
#define IN_DIM  256
#define OUT_DIM 128
#define S_SECT  8
#define K_BR    9
#define NK      (K_BR*OUT_DIM)   // 1152
#define EP_EDGE 40000
#define N_EDGES (S_SECT*EP_EDGE) // 320000
#define N_BINS  (S_SECT*N_NODES) // 160000
#define SCAN_BLOCKS 160
#define M_ROWS  (N_NODES*K_BR)   // 180000
#define ZP      136              // B LDS pitch (shorts): 272B, 16B-aligned, 2-way banks (free)
#define TP      136              // Z-tile pitch (shorts), bank-safe for gram-phase frag reads

typedef float v4f __attribute__((ext_vector_type(4)));
typedef short v8s __attribute__((ext_vector_type(8)));

__device__ inline unsigned short f2bf(float f) {
  union { float f; unsigned u; } v; v.f = f;
  unsigned r = v.u + 0x7fff + ((v.u >> 16) & 1);   // RNE
  return (unsigned short)(r >> 16);
}
__device__ inline float bf2f(unsigned short h) {
  union { unsigned u; float f; } v; v.u = ((unsigned)h) << 16;
  return v.f;
}

// merged prep: Wtg[j][k] = bf16(Wcat[k][j]) then Btg[n][k] = bf16([WC|WD][k][n])
__global__ __launch_bounds__(256) void k_prep(
    const float* __restrict__ Wself, const float* __restrict__ Wsect,
    const float* __restrict__ WC, const float* __restrict__ WD,
    unsigned short* __restrict__ Wtg, unsigned short* __restrict__ Btg)
{
  const int id = blockIdx.x * 256 + threadIdx.x;      // 294912 + 32768
  if (id < NK*IN_DIM) {
    const int j = id >> 8, k = id & 255;
    float w;
    if (j < OUT_DIM) w = Wself[(size_t)k*OUT_DIM + j];
    else {
      const int s = (j - OUT_DIM) >> 7, c = (j - OUT_DIM) & 127;
      w = Wsect[(size_t)s*(IN_DIM*OUT_DIM) + (size_t)k*OUT_DIM + c];
    }
    Wtg[id] = f2bf(w);
  } else {
    const int id2 = id - NK*IN_DIM;
    if (id2 < 256*128) {
      const int n = id2 >> 7, k = id2 & 127;
      const float w = (n < OUT_DIM) ? WC[k*OUT_DIM + n] : WD[k*OUT_DIM + (n - OUT_DIM)];
      Btg[id2] = f2bf(w);
    }
  }
}

// ---------------------------------------------------------------------------
// Kernel A (MFMA+LDS): P = x @ Wtg^T.
// Grid (313,3): 64 rows/block (4 waves x 16 rows), 3 branches per block.
// ---------------------------------------------------------------------------
__global__ __launch_bounds__(256, 4) void k_gemm_xw_mfma(
    const float* __restrict__ x, const unsigned short* __restrict__ Wtg,
    const float* __restrict__ outn, const float* __restrict__ inn,
    unsigned short* __restrict__ Hbuf, unsigned short* __restrict__ Zbufh)
{
  __shared__ unsigned short Bls[128*ZP];   // 34816 B
  const int t = threadIdx.x;
  const int wave = t >> 6, lane = t & 63;
  const int mrow = lane & 15, quad = lane >> 4;
  const int m0 = blockIdx.x * 64 + wave * 16;

  // A fragments, full K (32 VGPR), converted once
  v8s afr[8];
  {
    const int r = m0 + mrow;
    const bool ok = (r < N_NODES);
    const float* src = x + (size_t)r*IN_DIM + quad*8;
    #pragma unroll
    for (int kq = 0; kq < 8; ++kq) {
      float4 a0 = {0.f,0.f,0.f,0.f}, a1 = {0.f,0.f,0.f,0.f};
      if (ok) {
        a0 = *(const float4*)(src + kq*32);
        a1 = *(const float4*)(src + kq*32 + 4);
      }
      v8s f;
      f[0] = (short)f2bf(a0.x); f[1] = (short)f2bf(a0.y);
      f[2] = (short)f2bf(a0.z); f[3] = (short)f2bf(a0.w);
      f[4] = (short)f2bf(a1.x); f[5] = (short)f2bf(a1.y);
      f[6] = (short)f2bf(a1.z); f[7] = (short)f2bf(a1.w);
      afr[kq] = f;
    }
  }

  for (int jj = 0; jj < 3; ++jj) {
    const int jb = blockIdx.y * 3 + jj;       // global branch 0..8

    v4f acc[8];
    #pragma unroll
    for (int jt = 0; jt < 8; ++jt) acc[jt] = (v4f){0.f,0.f,0.f,0.f};

    for (int kh = 0; kh < 2; ++kh) {
      #pragma unroll
      for (int i = 0; i < 8; ++i) {
        const int idx = t + i*256;            // 0..2047
        const int row = idx >> 4, c8 = idx & 15;
        *(uint4*)(Bls + row*ZP + c8*8) =
            *(const uint4*)(Wtg + (size_t)(jb*128 + row)*IN_DIM + kh*128 + c8*8);
      }
      __syncthreads();

      #pragma unroll
      for (int kq = 0; kq < 4; ++kq) {
        #pragma unroll
        for (int jt = 0; jt < 8; ++jt) {
          const v8s bf = *(const v8s*)(Bls + (jt*16 + mrow)*ZP + kq*32 + quad*8);
          acc[jt] = __builtin_amdgcn_mfma_f32_16x16x32_bf16(afr[kh*4 + kq], bf, acc[jt], 0, 0, 0);
        }
      }
      __syncthreads();   // protect LDS before restaging
    }

    if (jb == 0) {
      #pragma unroll
      for (int p = 0; p < 4; ++p) {
        const int R = m0 + quad*4 + p;
        if (R >= N_NODES) continue;
        const float iw = inn[R];
        #pragma unroll
        for (int jt = 0; jt < 8; ++jt)
          Zbufh[(size_t)R*NK + jt*16 + mrow] = f2bf(acc[jt][p] * iw);
      }
    } else {
      const int s = jb - 1;
      #pragma unroll
      for (int p = 0; p < 4; ++p) {
        const int R = m0 + quad*4 + p;
        if (R >= N_NODES) continue;
        const float ow = outn[R];
        #pragma unroll
        for (int jt = 0; jt < 8; ++jt)
          Hbuf[((size_t)s*N_NODES + R)*OUT_DIM + jt*16 + mrow] = f2bf(acc[jt][p] * ow);
      }
    }
  }
}

// ---------------------------------------------------------------------------
// CSR build: count -> scan(3) -> scatter
// ---------------------------------------------------------------------------
__global__ __launch_bounds__(256) void k_count(
    const int* __restrict__ rows, int* __restrict__ cnt)
{
  const int id = blockIdx.x * 256 + threadIdx.x;
  if (id >= N_EDGES) return;
  const int s = id / EP_EDGE;
  atomicAdd(&cnt[s * N_NODES + rows[id]], 1);
}

__global__ __launch_bounds__(256) void k_scan1(
    const int* __restrict__ cnt, int* __restrict__ bsum)
{
  __shared__ int sh[256];
  const int t = threadIdx.x;
  const int base = blockIdx.x * 1000;
  int s = 0;
  if (t < 250) {
    const int i = base + t*4;
    s = cnt[i] + cnt[i+1] + cnt[i+2] + cnt[i+3];
  }
  sh[t] = s; __syncthreads();
  for (int off = 128; off > 0; off >>= 1) {
    if (t < off) sh[t] += sh[t + off];
    __syncthreads();
  }
  if (t == 0) bsum[blockIdx.x] = sh[0];
}

__global__ void k_scan2(const int* __restrict__ bsum, int* __restrict__ boff)
{
  if (threadIdx.x == 0) {
    int acc = 0;
    for (int b = 0; b < SCAN_BLOCKS; ++b) { boff[b] = acc; acc += bsum[b]; }
  }
}

__global__ __launch_bounds__(256) void k_scan3(
    const int* __restrict__ cnt, const int* __restrict__ boff,
    int* __restrict__ offs)
{
  __shared__ int sh[256];
  const int t = threadIdx.x;
  const int base = blockIdx.x * 1000;
  int v[4] = {0,0,0,0};
  int mySum = 0;
  if (t < 250) {
    const int i = base + t*4;
    v[0]=cnt[i]; v[1]=cnt[i+1]; v[2]=cnt[i+2]; v[3]=cnt[i+3];
    mySum = v[0]+v[1]+v[2]+v[3];
  }
  sh[t] = mySum; __syncthreads();
  for (int off = 1; off < 256; off <<= 1) {
    int add = (t >= off) ? sh[t - off] : 0;
    __syncthreads();
    sh[t] += add;
    __syncthreads();
  }
  if (t < 250) {
    int excl = boff[blockIdx.x] + sh[t] - mySum;
    const int i = base + t*4;
    offs[i]   = excl;           excl += v[0];
    offs[i+1] = excl;           excl += v[1];
    offs[i+2] = excl;           excl += v[2];
    offs[i+3] = excl;
  }
}

__global__ __launch_bounds__(256) void k_scatter(
    const int* __restrict__ rows, const int* __restrict__ cols,
    const int* __restrict__ offs, int* __restrict__ cur,
    int* __restrict__ eCol)
{
  const int id = blockIdx.x * 256 + threadIdx.x;
  if (id >= N_EDGES) return;
  const int s = id / EP_EDGE;
  const int bin = s * N_NODES + rows[id];
  const int pos = offs[bin] + atomicAdd(&cur[bin], 1);
  eCol[pos] = cols[id];
}

// ---------------------------------------------------------------------------
// Kernel B': pull aggregation from bf16 Hbuf; fold in_norm; bf16 store.
// ---------------------------------------------------------------------------
__global__ __launch_bounds__(256) void k_agg_csr(
    const unsigned short* __restrict__ Hbuf, const int* __restrict__ offs,
    const int* __restrict__ cnt, const int* __restrict__ eCol,
    const float* __restrict__ inn, unsigned short* __restrict__ Zbufh)
{
  const long long tid = (long long)blockIdx.x * 256 + threadIdx.x;
  const int group = (int)(tid >> 5);
  if (group >= N_BINS) return;
  const int lane = (int)(tid & 31);
  const int s = group / N_NODES;
  const int r = group - s * N_NODES;
  const int start = offs[group];
  const int n = cnt[group];
  float4 acc = {0.f, 0.f, 0.f, 0.f};
  for (int i = 0; i < n; ++i) {
    const int c = eCol[start + i];
    const uint2 h = *(const uint2*)(Hbuf + ((size_t)s*N_NODES + c)*OUT_DIM + lane*4);
    acc.x += bf2f((unsigned short)h.x);
    acc.y += bf2f((unsigned short)(h.x >> 16));
    acc.z += bf2f((unsigned short)h.y);
    acc.w += bf2f((unsigned short)(h.y >> 16));
  }
  const float w = inn[r];
  uint2 o;
  o.x = (unsigned)f2bf(acc.x * w) | ((unsigned)f2bf(acc.y * w) << 16);
  o.y = (unsigned)f2bf(acc.z * w) | ((unsigned)f2bf(acc.w * w) << 16);
  *(uint2*)(Zbufh + ((size_t)r*K_BR + 1 + s)*OUT_DIM + lane*4) = o;
}

// ---------------------------------------------------------------------------
// k_zcd_interact: FUSED [zc|zd] GEMM + gram + softmax + combine + gate.
// 512 threads / 8 waves / 8 nodes per block: wave w owns node w EVERYWHERE.
// B staged via LDS (Bls, 64-row stages — round-5 structure; round-6's
// global-B read was a 640 MB L2 stream and regressed 60%).
// GEMM uses swapped mfma operands -> lane holds 4 consecutive channels of
// one z-row -> packed ds_write_b64 tls stores (harness-verified in r6).
// After GEMM, all LDS (tls/graw/gs) is wave-private: no barriers.
// LDS 68.1 KB -> 2 blocks/CU = 16 waves/CU (2x round-5 concurrency);
// per-wave serial work halved (1 node instead of 2).
// ---------------------------------------------------------------------------
__global__ __launch_bounds__(512, 4) void k_zcd_interact(
    const unsigned short* __restrict__ Zbufh, const unsigned short* __restrict__ Btg,
    const float* __restrict__ gw, const float* __restrict__ gb,
    float* __restrict__ out)
{
  __shared__ unsigned short Bls[64*ZP];        // 17408 B
  __shared__ unsigned short tls[8][2][9*TP];   // 39168 B (wave-private slices)
  __shared__ float graw[8][2][K_BR][10];       // 5760 B
  __shared__ float gs[8][2][K_BR][10];         // 5760 B
  const int t = threadIdx.x;
  const int wv = t >> 6, lane = t & 63;
  const int mrow = lane & 15, quad = lane >> 4;
  const int n0 = blockIdx.x * 8;
  const int rowbase = (n0 + wv)*9;

  // ---- A-frags: the wave's 9 rows of Zbufh (1 M-tile, rows 0..8 valid)
  v8s afr[4];
  {
    const bool ok = (mrow < 9);
    const unsigned short* src = Zbufh + (size_t)(rowbase + mrow)*OUT_DIM + quad*8;
    #pragma unroll
    for (int kq = 0; kq < 4; ++kq) {
      v8s f = {0,0,0,0,0,0,0,0};
      if (ok) f = *(const v8s*)(src + kq*32);
      afr[kq] = f;
    }
  }

  // ---- GEMM phase: zc (jh=0) then zd (jh=1); swapped operands; acc -> tls
  for (int jh = 0; jh < 2; ++jh) {
    v4f acc[8];
    #pragma unroll
    for (int j = 0; j < 8; ++j) acc[j] = (v4f){0.f,0.f,0.f,0.f};

    for (int sub = 0; sub < 2; ++sub) {
      // stage 64 B-rows (channels jh*128 + sub*64 .. +63) into LDS
      #pragma unroll
      for (int i = 0; i < 2; ++i) {
        const int idx = t + i*512;     // 0..1023
        const int row = idx >> 4, c8 = idx & 15;
        *(uint4*)(Bls + row*ZP + c8*8) =
            *(const uint4*)(Btg + (size_t)(jh*128 + sub*64 + row)*OUT_DIM + c8*8);
      }
      __syncthreads();
      #pragma unroll
      for (int jl = 0; jl < 4; ++jl) {
        const unsigned short* bp = Bls + (jl*16 + mrow)*ZP + quad*8;
        #pragma unroll
        for (int kq = 0; kq < 4; ++kq) {
          const v8s bf = *(const v8s*)(bp + kq*32);
          // swapped: lane holds channel n = jl*16+quad*4+p, z-row m = mrow
          acc[sub*4+jl] = __builtin_amdgcn_mfma_f32_16x16x32_bf16(bf, afr[kq], acc[sub*4+jl], 0, 0, 0);
        }
      }
      __syncthreads();   // protect Bls before restaging
    }

    // store: packed b64 per acc slot; same f2bf rounding as unfused ZCD.
    if (mrow < 9) {
      unsigned short* dst = &tls[wv][jh][mrow*TP];
      #pragma unroll
      for (int a = 0; a < 8; ++a) {
        const int off = (a >> 2)*64 + (a & 3)*16 + quad*4;
        uint2 o;
        o.x = (unsigned)f2bf(acc[a][0]) | ((unsigned)f2bf(acc[a][1]) << 16);
        o.y = (unsigned)f2bf(acc[a][2]) | ((unsigned)f2bf(acc[a][3]) << 16);
        *(uint2*)(dst + off) = o;
      }
    }
  }
  // tls is wave-private from here on; same-wave DS ordering suffices.

  // ---- gram phase: G = Z·Z^T via MFMA, frags re-read from tls
  {
    const int r = lane & 15;
    #pragma unroll
    for (int mat = 0; mat < 2; ++mat) {
      const unsigned short* src = &tls[wv][mat][r*TP + quad*8];
      v8s frag[4];
      #pragma unroll
      for (int kq = 0; kq < 4; ++kq) {
        v8s f = {0,0,0,0,0,0,0,0};
        if (r < K_BR) f = *(const v8s*)(src + kq*32);
        frag[kq] = f;
      }
      v4f acc = {0.f,0.f,0.f,0.f};
      #pragma unroll
      for (int kq = 0; kq < 4; ++kq)
        acc = __builtin_amdgcn_mfma_f32_16x16x32_bf16(frag[kq], frag[kq], acc, 0, 0, 0);
      if (r < K_BR) {
        #pragma unroll
        for (int p = 0; p < 4; ++p) {
          const int m = quad*4 + p;
          if (m < K_BR) graw[wv][mat][m][r] = acc[p];
        }
      }
    }
  }

  // ---- softmax phase: wave-local (lanes 0..17 cover 2 mats x 9 rows)
  if (lane < 18) {
    const int mat = (lane >= 9) ? 1 : 0;
    const int k   = lane - mat*9;
    float v[9];
    if (mat == 0) {
      #pragma unroll
      for (int j = 0; j < 9; ++j) v[j] = graw[wv][0][k][j];
    } else {
      const float gkk = graw[wv][1][k][k];
      #pragma unroll
      for (int j = 0; j < 9; ++j) v[j] = gkk - graw[wv][1][k][j];
    }
    float m = v[0];
    #pragma unroll
    for (int j = 1; j < 9; ++j) m = fmaxf(m, v[j]);
    float sum = 0.f;
    #pragma unroll
    for (int j = 0; j < 9; ++j) { v[j] = expf(v[j] - m); sum += v[j]; }
    const float inv = 1.f / sum;
    #pragma unroll
    for (int j = 0; j < 9; ++j) gs[wv][mat][k][j] = v[j] * inv;
  }

  // ---- combine + gate, wave-local, barrier-free (1 node = wv)
  const float gbv = gb[0];
  float gwc[2][9], gwd[2][9];
  #pragma unroll
  for (int dd = 0; dd < 2; ++dd) {
    const int d = lane + dd*64;
    #pragma unroll
    for (int j = 0; j < 9; ++j) {
      gwc[dd][j] = gw[j*OUT_DIM + d];
      gwd[dd][j] = gw[NK + j*OUT_DIM + d];
    }
  }

  float zcj[2][9], zdj[2][9];
  #pragma unroll
  for (int dd = 0; dd < 2; ++dd) {
    const int d = lane + dd*64;
    #pragma unroll
    for (int j = 0; j < 9; ++j) {
      zcj[dd][j] = bf2f(tls[wv][0][j*TP + d]);
      zdj[dd][j] = bf2f(tls[wv][1][j*TP + d]);
    }
  }
  float zcomK[2][9], zdisK[2][9];
  float gp = 0.f;
  #pragma unroll
  for (int k = 0; k < 9; ++k) {
    #pragma unroll
    for (int dd = 0; dd < 2; ++dd) {
      float zc = 0.f, ad = 0.f;
      #pragma unroll
      for (int j = 0; j < 9; ++j) {
        zc += gs[wv][0][k][j] * zcj[dd][j];
        ad += gs[wv][1][k][j] * zdj[dd][j];
      }
      zcomK[dd][k] = zc;
      zdisK[dd][k] = zdj[dd][k] - ad;
      gp += zc * gwc[dd][k] + zdisK[dd][k] * gwd[dd][k];
    }
  }
  #pragma unroll
  for (int off = 32; off > 0; off >>= 1) gp += __shfl_xor(gp, off, 64);
  const float beta = 1.f / (1.f + expf(-(gp + gbv)));
  #pragma unroll
  for (int k = 0; k < 9; ++k) {
    #pragma unroll
    for (int dd = 0; dd < 2; ++dd) {
      const int d = lane + dd*64;
      out[(size_t)(n0+wv)*NK + k*OUT_DIM + d] =
          beta*zcomK[dd][k] + (1.f-beta)*zdisK[dd][k];
    }
  }
}

// ---------------------------------------------------------------------------
extern "C" void kernel_launch(void* const* d_in, const int* in_sizes, int n_in,
                              void* d_out, int out_size, void* d_ws, size_t ws_size,
                              hipStream_t stream)
{
  const float* x     = (const float*)d_in[0];
  const float* Wself = (const float*)d_in[1];
  const float* Wsect = (const float*)d_in[2];
  const float* WC    = (const float*)d_in[3];
  const float* WD    = (const float*)d_in[4];
  const float* gw    = (const float*)d_in[5];
  const float* gb    = (const float*)d_in[6];
  const float* outn  = (const float*)d_in[7];
  const float* inn   = (const float*)d_in[8];
  const int*   rows  = (const int*)d_in[9];
  const int*   cols  = (const int*)d_in[10];
  float* out = (float*)d_out;

  char* p = (char*)d_ws;
  unsigned short* Hbuf  = (unsigned short*)p; p += (size_t)S_SECT*N_NODES*OUT_DIM*2;
  unsigned short* Zbufh = (unsigned short*)p; p += (size_t)M_ROWS*OUT_DIM*2;
  int* cnt    = (int*)p;                      p += (size_t)N_BINS*4;
  int* offs   = (int*)p;                      p += (size_t)N_BINS*4;
  int* cur    = (int*)p;                      p += (size_t)N_BINS*4;
  int* bsum   = (int*)p;                      p += 256*4;
  int* boff   = (int*)p;                      p += 256*4;
  int* eCol   = (int*)p;                      p += (size_t)N_EDGES*4;
  unsigned short* Btg = (unsigned short*)p;   p += 256*128*2;
  unsigned short* Wtg = (unsigned short*)p;   p += (size_t)NK*IN_DIM*2;

  hipMemsetAsync(cnt, 0, (size_t)N_BINS*4, stream);
  hipMemsetAsync(cur, 0, (size_t)N_BINS*4, stream);

  k_prep<<<(NK*IN_DIM + 256*128 + 255)/256, 256, 0, stream>>>(Wself, Wsect, WC, WD, Wtg, Btg);

  dim3 gA((N_NODES + 63)/64, 3);   // 313 x 3
  k_gemm_xw_mfma<<<gA, 256, 0, stream>>>(x, Wtg, outn, inn, Hbuf, Zbufh);

  const int eb = (N_EDGES + 255)/256;
  k_count  <<<eb, 256, 0, stream>>>(rows, cnt);
  k_scan1  <<<SCAN_BLOCKS, 256, 0, stream>>>(cnt, bsum);
  k_scan2  <<<1, 64, 0, stream>>>(bsum, boff);
  k_scan3  <<<SCAN_BLOCKS, 256, 0, stream>>>(cnt, boff, offs);
  k_scatter<<<eb, 256, 0, stream>>>(rows, cols, offs, cur, eCol);

  const int aggBlocks = (N_BINS*32 + 255)/256;
  k_agg_csr<<<aggBlocks, 256, 0, stream>>>(Hbuf, offs, cnt, eCol, inn, Zbufh);

  k_zcd_interact<<<N_NODES/8, 512, 0, stream>>>(Zbufh, Btg, gw, gb, out);
}